// Round 1
// baseline (93.998 us; speedup 1.0000x reference)
//
#include <hip/hip_runtime.h>
#include <hip/hip_fp16.h>
#include <stdint.h>

#define N 512
#define NA 180
#define TD 64           // detectors per block
#define TW 96           // LDS tile pitch in pair-dwords
#define TILE_DW (36 * 256)          // 9216 dw = 36864 B per buffer; x2 buffers = 73728 B -> 2 blocks/CU
#define PP 708          // padded pair-image pitch (dwords)
#define PR 704          // padded pair-image rows
#define POFF 96         // padded index of image row/col 0

// d_ws float-offsets
#define WS_IMGPB  0
#define WS_IMGTPB (PR * PP)                 // 498432
#define WS_TAB    (2 * PR * PP)             // 996864 (16B aligned)
#define WS_FLAGS  (WS_TAB + 4 * NA)

typedef _Float16 hh2 __attribute__((ext_vector_type(2)));
union H2U { uint32_t u; hh2 h; };

__device__ __forceinline__ hh2 cvt_pkrtz(float a, float b) {
    return __builtin_bit_cast(hh2, __builtin_amdgcn_cvt_pkrtz(a, b));
}

__device__ __forceinline__ void load16_to_lds(const uint32_t* g, uint32_t* l) {
    __builtin_amdgcn_global_load_lds(
        (const __attribute__((address_space(1))) void*)g,
        (__attribute__((address_space(3))) void*)l,
        16 /*bytes*/, 0 /*offset*/, 0 /*aux*/);
}

// Tiled pad, now 22x22 blocks of 32x32 (484 blocks ~ 2/CU, was 121 ~ 0.5/CU):
// builds padded fp16-pair image (imgPB[r][c] = (h(I[r][c]), h(I[r][c+1]))) and
// its transpose, all accesses coalesced; also the per-angle table.
__global__ __launch_bounds__(256) void pad_kernel(const float* __restrict__ img,
                                                  const int* __restrict__ angles,
                                                  uint32_t* __restrict__ imgPB,
                                                  uint32_t* __restrict__ imgTPB,
                                                  float4* __restrict__ tab,
                                                  int* __restrict__ flags) {
    __shared__ float lds[33 * 34];   // pitch 34
    const int tid = threadIdx.x;
    const int bx = blockIdx.x, by = blockIdx.y;

    if (bx == 0 && by == 0 && tid < NA) {
        float t = (float)angles[tid] * 0.017453292519943295f;
        float si = sinf(t), co = cosf(t);
        int useT = fabsf(si) > fabsf(co);
        float4 e;
        if (useT) { e.x = co; e.y = -si; e.z = si; e.w = co; }
        else      { e.x = si; e.y = co;  e.z = co; e.w = -si; }
        tab[tid] = e;                // (au, bus, av, bvs)
        flags[tid] = useT;
    }

    // stage 33x33 of the padded image: padded coords (by*32+r, bx*32+c)
    for (int idx = tid; idx < 33 * 33; idx += 256) {
        int r = idx / 33, cc = idx - r * 33;
        int y = by * 32 + r - POFF, x = bx * 32 + cc - POFF;
        bool in = ((unsigned)y < N) && ((unsigned)x < N);
        lds[r * 34 + cc] = in ? img[y * N + x] : 0.0f;
    }
    __syncthreads();
    const int r0 = tid >> 5, cl = tid & 31;
#pragma unroll
    for (int j = 0; j < 4; ++j) {
        int row = j * 8 + r0;
        float v0 = lds[row * 34 + cl], v1 = lds[row * 34 + cl + 1];
        __half2 h = __halves2half2(__float2half(v0), __float2half(v1));
        imgPB[(size_t)(by * 32 + row) * PP + bx * 32 + cl] = *(uint32_t*)&h;
        float t0 = lds[cl * 34 + row], t1 = lds[(cl + 1) * 34 + row];
        __half2 ht = __halves2half2(__float2half(t0), __float2half(t1));
        imgTPB[(size_t)(bx * 32 + row) * PP + by * 32 + cl] = *(uint32_t*)&ht;
    }
}

// One block = (1 angle, 64 detectors, ALL 512 i), eight 64-i phases.
// NEW: double-buffered pipelined staging. Per live phase: issue NEXT phase's
// global_load_lds into buf^1 BEFORE sampling current buf, so the implicit
// vmcnt(0) drain at the end-of-phase __syncthreads() lands AFTER ~400+ cycles
// of sampling work (drain-late) instead of stalling the phase head.
// One barrier per phase (was two). LDS 2x36864 -> 2 blocks/CU.
__global__ __launch_bounds__(512, 4) void radon_kernel(const uint32_t* __restrict__ imgPB,
                                                       const uint32_t* __restrict__ imgTPB,
                                                       const float4* __restrict__ tab,
                                                       const int* __restrict__ flags,
                                                       float* __restrict__ out) {
    __shared__ uint32_t tile[2 * TILE_DW];

    const int tid  = threadIdx.x;
    const int lane = tid & 63;
    const int wave = tid >> 6;           // 0..7
    const int d0 = blockIdx.x * TD;
    const int a  = blockIdx.y;

    const float c = 255.5f;
    const float4 tb = tab[a];
    const float au = tb.x, bus = tb.y, av = tb.z, bvs = tb.w;

    // d-extremes of the affine offset (fixed for the whole block)
    const float xc0 = (float)d0 - c, xc1 = (float)(d0 + TD - 1) - c;
    const float buA = fmaf(bus, xc0, c), buB = fmaf(bus, xc1, c);
    const float bvA = fmaf(bvs, xc0, c), bvB = fmaf(bvs, xc1, c);
    const float buMin = fminf(buA, buB), buMax = fmaxf(buA, buB);
    const float bvMin = fminf(bvA, bvB), bvMax = fmaxf(bvA, bvB);

    const uint32_t* __restrict__ src = flags[a] ? imgTPB : imgPB;

    // per-lane affine offsets (shared by all phases)
    const float xcl = (float)(d0 + lane) - c;
    const float buLb = fmaf(bus, xcl, c);
    const float bvLb = fmaf(bvs, xcl, c);

    // incremental staging address bases (per lane, shared by all phases)
    const int t0g  = wave * 256 + (lane << 2);   // dword index into tile
    const int q0   = t0g / TW;
    const int c0   = t0g - q0 * TW;
    const int goff0 = q0 * PP + c0;              // dword offset from gbase

    // phase params (block-uniform): live?, ub0, vb, nch
    auto params = [&](int p, int& ub0, int& vb, int& nch) -> bool {
        const int ip = p * 64;
        const float fi0 = (float)ip - c, fi1 = (float)(ip + 63) - c;
        const float fiLoU = (au >= 0.0f) ? fi0 : fi1, fiHiU = (au >= 0.0f) ? fi1 : fi0;
        const float fiLoV = (av >= 0.0f) ? fi0 : fi1, fiHiV = (av >= 0.0f) ? fi1 : fi0;
        const float umin = fmaf(au, fiLoU, buMin), umax = fmaf(au, fiHiU, buMax);
        const float vmin = fmaf(av, fiLoV, bvMin), vmax = fmaf(av, fiHiV, bvMax);
        if (umin > (float)N || umax < -1.0f || vmin > (float)N || vmax < -1.0f)
            return false;
        // >=1-texel margins; live phases have umin >= -90.3 so the 96-apron
        // keeps everything in-bounds (same geometry as verified baseline).
        ub0 = (((int)floorf(umin)) - 1) & ~3;
        vb  = ((int)floorf(vmin)) - 1;
        int rows = ((int)floorf(vmax)) + 3 - vb;     // <= 94
        nch = (rows * TW + 255) >> 8;                // <= 36
        return true;
    };

    auto stage = [&](int ub0, int vb, int nch, int base) {
        const uint32_t* gb = src + (vb + POFF) * PP + (ub0 + POFF) + goff0;
        int cc = c0;
#pragma unroll
        for (int st = 0; st < 5; ++st) {
            int chunk = st * 8 + wave;        // 0..39
            if (chunk < nch) load16_to_lds(gb, &tile[base + chunk * 256]);
            // advance by 2048 tile-dwords = 21 rows + 32 cols (mod 96)
            cc += 32;
            int wrap = (cc >= TW);
            cc = wrap ? cc - TW : cc;
            gb += 21 * PP + 32 + (wrap ? (PP - TW) : 0);
        }
    };

    float s = 0.0f;

    // find first live phase
    int pc = -1, ub0c = 0, vbc = 0, nchc = 0;
    for (int p = 0; p < 8; ++p) {
        if (params(p, ub0c, vbc, nchc)) { pc = p; break; }
    }

    int base = 0;
    if (pc >= 0) {
        stage(ub0c, vbc, nchc, base);   // prologue: only phase that pays full drain
        __syncthreads();
    }
    while (pc >= 0) {
        // look ahead to next live phase, issue its staging into the other buffer
        int pn = -1, ub0n = 0, vbn = 0, nchn = 0;
        for (int p = pc + 1; p < 8; ++p) {
            if (params(p, ub0n, vbn, nchn)) { pn = p; break; }
        }
        if (pn >= 0) stage(ub0n, vbn, nchn, base ^ TILE_DW);

        // sample current buffer (overlaps with in-flight next-phase DMA)
        {
            const float buL = buLb - (float)ub0c;   // tile-local fold
            const float bvL = bvLb - (float)vbc;
            const float fiw = (float)(pc * 64 + wave * 8) - c;
            float u = fmaf(au, fiw, buL);
            float v = fmaf(av, fiw, bvL);
            const uint32_t* tl = tile + base;
#pragma unroll
            for (int k = 0; k < 8; ++k) {
                float wx = __builtin_amdgcn_fractf(u);
                float wy = __builtin_amdgcn_fractf(v);
                int iu = (int)u, iv = (int)v;      // trunc == floor (u,v > 0)
                int ai = iv * TW + iu;
                H2U P0, P1;
                P0.u = tl[ai];
                P1.u = tl[ai + TW];                // ds_read2_b32 0/96
                hh2 wy2 = cvt_pkrtz(wy, wy);
                hh2 m   = wy2 * (P1.h - P0.h) + P0.h;   // pk f16 vertical lerp
                hh2 wv  = cvt_pkrtz(1.0f - wx, wx);
                s = __builtin_amdgcn_fdot2(wv, m, s, false);
                u += au;                           // incremental (drift < 1e-4 px)
                v += av;
            }
        }
        // drain-late: next-phase DMA had the whole sampling span to land;
        // also the WAR fence before buf^1 gets overwritten next iteration.
        __syncthreads();
        pc = pn; ub0c = ub0n; vbc = vbn; nchc = nchn;
        base ^= TILE_DW;
    }

    // ---- merge 8 wave-partials; plain store (sole owner of (d,a)) ----
    __syncthreads();
    float* ft = (float*)tile;
    ft[tid] = s;
    __syncthreads();
    if (tid < 64) {
        float r = ft[tid]       + ft[tid + 64]  + ft[tid + 128] + ft[tid + 192]
                + ft[tid + 256] + ft[tid + 320] + ft[tid + 384] + ft[tid + 448];
        out[(d0 + tid) * NA + a] = r;
    }
}

extern "C" void kernel_launch(void* const* d_in, const int* in_sizes, int n_in,
                              void* d_out, int out_size, void* d_ws, size_t ws_size,
                              hipStream_t stream) {
    const float* img  = (const float*)d_in[0];
    const int* angles = (const int*)d_in[1];
    float* out = (float*)d_out;
    float* ws  = (float*)d_ws;

    uint32_t* imgPB  = (uint32_t*)(ws + WS_IMGPB);
    uint32_t* imgTPB = (uint32_t*)(ws + WS_IMGTPB);
    float4*   tab    = (float4*)(ws + WS_TAB);
    int*      flags  = (int*)(ws + WS_FLAGS);

    dim3 pgrid(22, 22);
    pad_kernel<<<pgrid, 256, 0, stream>>>(img, angles, imgPB, imgTPB, tab, flags);

    dim3 grid(N / TD, NA);
    radon_kernel<<<grid, 512, 0, stream>>>(imgPB, imgTPB, tab, flags, out);
}